// Round 15
// baseline (227.482 us; speedup 1.0000x reference)
//
#include <hip/hip_runtime.h>
#include <cfloat>

#define NB 4
#define NN 4096
#define NC 256

typedef _Float16 f16;
typedef _Float16 f16x8 __attribute__((ext_vector_type(8)));
typedef float f32x4 __attribute__((ext_vector_type(4)));

__device__ __forceinline__ void gl_lds16(const void* g, void* l) {
    __builtin_amdgcn_global_load_lds(
        (const __attribute__((address_space(1))) unsigned int*)g,
        (__attribute__((address_space(3))) unsigned int*)l, 16, 0, 0);
}

// ---------------- prep: fp32 -> f16 hi/lo split + diag ----------------
__global__ __launch_bounds__(256) void prep_kernel(const float* __restrict__ x,
                                                   f16* __restrict__ xh,
                                                   f16* __restrict__ xl,
                                                   float* __restrict__ diag) {
    const int lane = threadIdx.x & 63;
    const int wave = threadIdx.x >> 6;
    const int row  = (blockIdx.x << 2) + wave;            // 0..16383
    const float4 v = ((const float4*)(x + (size_t)row * NC))[lane];
    union { f16 h[4]; uint2 u; } H, L;
    float vv[4] = {v.x, v.y, v.z, v.w};
    float s = 0.f;
    #pragma unroll
    for (int k = 0; k < 4; ++k) {
        H.h[k] = (f16)vv[k];
        L.h[k] = (f16)(vv[k] - (float)H.h[k]);
        s = fmaf(vv[k], vv[k], s);
    }
    *(uint2*)(xh + (size_t)row * NC + lane * 4) = H.u;
    *(uint2*)(xl + (size_t)row * NC + lane * 4) = L.u;
    #pragma unroll
    for (int off = 32; off; off >>= 1) s += __shfl_xor(s, off, 64);
    if (lane == 0) diag[row] = s;
}

// ---------------- shared tile machinery (r8, verified) ----------------
#define TI 64
#define TJ 256
#define KCB 32
#define NCHUNK (NC / KCB)    // 8 k-chunks per j-tile
#define NJT (NN / TJ)        // 16 j-tiles
#define NJOBS 544            // 64 diagonal + 480 upper (triangular) jobs/batch
#define NS 80                // partial slots/row: 16 row-slots + 64 col-slots

#define TRIPLE(RT, CT, AH, AL, BH, BL) \
    acc[RT][CT] = __builtin_amdgcn_mfma_f32_16x16x32_f16(AH, BH[CT], acc[RT][CT], 0, 0, 0); \
    acc[RT][CT] = __builtin_amdgcn_mfma_f32_16x16x32_f16(AH, BL[CT], acc[RT][CT], 0, 0, 0); \
    acc[RT][CT] = __builtin_amdgcn_mfma_f32_16x16x32_f16(AL, BH[CT], acc[RT][CT], 0, 0, 0);

#define QUARTER(RT, AH, AL, BH, BL) \
    TRIPLE(RT, 0, AH, AL, BH, BL) TRIPLE(RT, 1, AH, AL, BH, BL) \
    TRIPLE(RT, 2, AH, AL, BH, BL) TRIPLE(RT, 3, AH, AL, BH, BL)

#define RDA(DH, DL, RT, KN) \
    DH = *(const f16x8*)&Ah[((RT) * 16 + l15) * NC + ((((KN) * 4 + quad) ^ sw) * 8)]; \
    DL = *(const f16x8*)&Al[((RT) * 16 + l15) * NC + ((((KN) * 4 + quad) ^ sw) * 8)];

#define SB __builtin_amdgcn_sched_barrier(0)

// r8 CHUNK (multi-tile loop version, used by fcm_mfma fallback path)
#define CHUNK(KC, BHC, BLC, BHN, BLN, A3HC, A3LC, A3HN, A3LN) do { \
    asm volatile("s_waitcnt lgkmcnt(0)" ::: "memory"); \
    SB; \
    { \
        int jn = jt + (((KC) + 2) >> 3); if (jn >= NJT) jn = 0; \
        const int kn = ((KC) + 2) & 7; \
        f16* const dh = &Sh[(KC) & 1][w * 2048]; \
        f16* const dl = &Sl[(KC) & 1][w * 2048]; \
        _Pragma("unroll") \
        for (int t = 0; t < 4; ++t) { \
            const int col = jn * TJ + w * 64 + t * 16 + bcol; \
            const size_t goff = (size_t)col * NC + (size_t)(kn * KCB) + bslot * 8; \
            gl_lds16(xhb + goff, dh + t * 512); \
            gl_lds16(xlb + goff, dl + t * 512); \
        } \
    } \
    SB; \
    QUARTER(0, a0h, a0l, BHC, BLC) \
    RDA(a0h, a0l, 0, ((KC) + 1) & 7) \
    SB; \
    QUARTER(1, a1h, a1l, BHC, BLC) \
    RDA(a1h, a1l, 1, ((KC) + 1) & 7) \
    SB; \
    QUARTER(2, a2h, a2l, BHC, BLC) \
    asm volatile("s_waitcnt vmcnt(8)" ::: "memory"); \
    SB; \
    { \
        const f16* const rh = &Sh[((KC) + 1) & 1][w * 2048]; \
        const f16* const rl = &Sl[((KC) + 1) & 1][w * 2048]; \
        _Pragma("unroll") \
        for (int ct = 0; ct < 4; ++ct) { \
            const int c = ct * 16 + l15; \
            BHN[ct] = *(const f16x8*)&rh[c * KCB + gB]; \
            BLN[ct] = *(const f16x8*)&rl[c * KCB + gB]; \
        } \
    } \
    RDA(a2h, a2l, 2, ((KC) + 1) & 7) \
    RDA(A3HN, A3LN, 3, ((KC) + 1) & 7) \
    SB; \
    QUARTER(3, A3HC, A3LC, BHC, BLC) \
} while (0)

// single-tile CHUNK for symmetric jobs: jt fixed, prefetch wraps kn in-tile
#define CHUNK2(KC, BHC, BLC, BHN, BLN, A3HC, A3LC, A3HN, A3LN) do { \
    asm volatile("s_waitcnt lgkmcnt(0)" ::: "memory"); \
    SB; \
    { \
        const int kn = ((KC) + 2) & 7; \
        f16* const dh = &Sh[(KC) & 1][w * 2048]; \
        f16* const dl = &Sl[(KC) & 1][w * 2048]; \
        _Pragma("unroll") \
        for (int t = 0; t < 4; ++t) { \
            const int col = j0 + w * 64 + t * 16 + bcol; \
            const size_t goff = (size_t)col * NC + (size_t)(kn * KCB) + bslot * 8; \
            gl_lds16(xhb + goff, dh + t * 512); \
            gl_lds16(xlb + goff, dl + t * 512); \
        } \
    } \
    SB; \
    QUARTER(0, a0h, a0l, BHC, BLC) \
    RDA(a0h, a0l, 0, ((KC) + 1) & 7) \
    SB; \
    QUARTER(1, a1h, a1l, BHC, BLC) \
    RDA(a1h, a1l, 1, ((KC) + 1) & 7) \
    SB; \
    QUARTER(2, a2h, a2l, BHC, BLC) \
    asm volatile("s_waitcnt vmcnt(8)" ::: "memory"); \
    SB; \
    { \
        const f16* const rh = &Sh[((KC) + 1) & 1][w * 2048]; \
        const f16* const rl = &Sl[((KC) + 1) & 1][w * 2048]; \
        _Pragma("unroll") \
        for (int ct = 0; ct < 4; ++ct) { \
            const int c = ct * 16 + l15; \
            BHN[ct] = *(const f16x8*)&rh[c * KCB + gB]; \
            BLN[ct] = *(const f16x8*)&rl[c * KCB + gB]; \
        } \
    } \
    RDA(a2h, a2l, 2, ((KC) + 1) & 7) \
    RDA(A3HN, A3LN, 3, ((KC) + 1) & 7) \
    SB; \
    QUARTER(3, A3HC, A3LC, BHC, BLC) \
} while (0)

// ---------------- symmetric job kernel ----------------
// Each job = one (band b, j-tile jt) pair, computed ONCE.
// Diagonal jobs (jt == b>>2): row-fold only (self-masked) — covers all
// same-group pairs. Upper jobs (jt > b>>2): row-fold for band b AND
// column-fold (per-column top-2 over band b's 64 rows, key diag[i]-2dot).
// Both record types store key = diag[partner] - 2*dot; reduce adds own diag.
// Partials P[batch][slot][row] float4(m1, i1bits, m2, 0): slot jt (0..15)
// for row-folds, slot 16+b for column-folds — each slot written by exactly
// one job (race-free). Unwritten slots preset to 0x7f7f7f7f (huge).
__global__ __launch_bounds__(256, 1) void fcm_sym(const f16* __restrict__ xh,
                                                  const f16* __restrict__ xl,
                                                  const float* __restrict__ diag,
                                                  float4* __restrict__ P) {
    __shared__ f16 Ah[TI * NC];          // 32 KB  persistent A hi (swizzled)
    __shared__ f16 Al[TI * NC];          // 32 KB  persistent A lo
    __shared__ f16 Sh[2][4 * 2048];      // 32 KB  B hi stripes, double-buffered
    __shared__ f16 Sl[2][4 * 2048];      // 32 KB  B lo stripes, double-buffered
    __shared__ float Dall[NN];           // 16 KB  full batch diag
    __shared__ float Scr[TI * 4 * 3];    // 3 KB   cross-wave merge

    const int tid   = threadIdx.x;
    const int bx    = blockIdx.x;
    const int batch = bx & 3;                         // spread batches across XCDs
    const int job   = bx >> 2;                        // 0..543

    // job -> (band b, tile jt)
    int b, jt;
    const bool isDiag = (job < 64);
    if (isDiag) {
        b  = job;
        jt = job >> 2;
    } else {
        int u = job - 64, g = 0;                      // 480 upper jobs
        while (g < 15 && u >= 4 * (15 - g)) { u -= 4 * (15 - g); ++g; }
        const int per = 15 - g;                       // >= 1
        b  = (g << 2) + u / per;
        jt = g + 1 + (u - (u / per) * per);
    }
    const int i0 = b * TI;
    const int j0 = jt * TJ;

    const f16* __restrict__ xhb = xh + (size_t)batch * NN * NC;
    const f16* __restrict__ xlb = xl + (size_t)batch * NN * NC;
    const float* __restrict__ db = diag + (size_t)batch * NN;

    const int w    = tid >> 6;    // 0..3
    const int lane = tid & 63;
    const int quad = lane >> 4;
    const int l15  = lane & 15;
    const int sw   = l15 & 7;

    // ---- A stage (once): LDS[row][granule ^ (row&7)] ----
    {
        const int rsub = lane >> 5;
        const int s    = lane & 31;
        #pragma unroll
        for (int it = 0; it < 8; ++it) {
            const int t  = w * 8 + it;
            const int rg = t * 2 + rsub;
            const int g  = s ^ (rg & 7);
            const size_t goff = (size_t)(i0 + rg) * NC + g * 8;
            gl_lds16(xhb + goff, Ah + t * 512);
            gl_lds16(xlb + goff, Al + t * 512);
        }
    }
    // ---- diag stage (per-lane global source — r7 bug-fix) ----
    #pragma unroll
    for (int t = 0; t < 4; ++t) {
        const int seg = (w * 4 + t) * 256;
        gl_lds16(db + seg + lane * 4, Dall + seg);
    }

    const int bcol  = lane >> 2;
    const int bslot = (lane & 3) ^ ((lane >> 3) & 3);
    const int gB    = (quad ^ ((l15 >> 1) & 3)) * 8;

    // ---- prologue: stage chunk 0 -> buf0, chunk 1 -> buf1 (tile jt) ----
    #pragma unroll
    for (int t = 0; t < 4; ++t) {
        const int col = j0 + w * 64 + t * 16 + bcol;
        gl_lds16(xhb + (size_t)col * NC + bslot * 8, &Sh[0][w * 2048] + t * 512);
        gl_lds16(xlb + (size_t)col * NC + bslot * 8, &Sl[0][w * 2048] + t * 512);
    }
    #pragma unroll
    for (int t = 0; t < 4; ++t) {
        const int col = j0 + w * 64 + t * 16 + bcol;
        gl_lds16(xhb + (size_t)col * NC + KCB + bslot * 8, &Sh[1][w * 2048] + t * 512);
        gl_lds16(xlb + (size_t)col * NC + KCB + bslot * 8, &Sl[1][w * 2048] + t * 512);
    }
    __syncthreads();

    f16x8 a0h, a0l, a1h, a1l, a2h, a2l, a3hA, a3lA, a3hB, a3lB;
    f16x8 bAh[4], bAl[4], bBh[4], bBl[4];

    #pragma unroll
    for (int ct = 0; ct < 4; ++ct) {
        const int c = ct * 16 + l15;
        bAh[ct] = *(const f16x8*)&Sh[0][w * 2048 + c * KCB + gB];
        bAl[ct] = *(const f16x8*)&Sl[0][w * 2048 + c * KCB + gB];
    }
    RDA(a0h, a0l, 0, 0) RDA(a1h, a1l, 1, 0) RDA(a2h, a2l, 2, 0) RDA(a3hA, a3lA, 3, 0)
    asm volatile("s_waitcnt lgkmcnt(0)" ::: "memory");
    SB;

    f32x4 acc[4][4];
    #pragma unroll
    for (int rt = 0; rt < 4; ++rt)
        #pragma unroll
        for (int ct = 0; ct < 4; ++ct)
            acc[rt][ct] = (f32x4){0.f, 0.f, 0.f, 0.f};

    CHUNK2(0, bAh, bAl, bBh, bBl, a3hA, a3lA, a3hB, a3lB);
    CHUNK2(1, bBh, bBl, bAh, bAl, a3hB, a3lB, a3hA, a3lA);
    CHUNK2(2, bAh, bAl, bBh, bBl, a3hA, a3lA, a3hB, a3lB);
    CHUNK2(3, bBh, bBl, bAh, bAl, a3hB, a3lB, a3hA, a3lA);
    CHUNK2(4, bAh, bAl, bBh, bBl, a3hA, a3lA, a3hB, a3lB);
    CHUNK2(5, bBh, bBl, bAh, bAl, a3hB, a3lB, a3hA, a3lA);
    CHUNK2(6, bAh, bAl, bBh, bBl, a3hA, a3lA, a3hB, a3lB);
    CHUNK2(7, bBh, bBl, bAh, bAl, a3hB, a3lB, a3hA, a3lA);

    // ---- column-fold (upper jobs only): per-column top-2 over band b rows ----
    if (!isDiag) {
        #pragma unroll
        for (int ct = 0; ct < 4; ++ct) {
            float c1 = FLT_MAX, c2 = FLT_MAX; int cix = 0x7fffffff;
            #pragma unroll
            for (int s = 0; s < 16; ++s) {             // increasing i order
                const int ii = i0 + (s >> 2) * 16 + quad * 4 + (s & 3);
                const float v = fmaf(-2.0f, acc[s >> 2][ct][s & 3], Dall[ii]);
                const bool lt = v < c1;
                c2 = fminf(c2, fmaxf(c1, v));
                c1 = fminf(c1, v);
                cix = lt ? ii : cix;
            }
            #pragma unroll
            for (int msk = 16; msk < 64; msk <<= 1) {  // merge across quads
                const float o1 = __shfl_xor(c1, msk, 64);
                const float o2 = __shfl_xor(c2, msk, 64);
                const int   oi = __shfl_xor(cix, msk, 64);
                const bool take = (o1 < c1) || (o1 == c1 && oi < cix);
                const float keep = take ? c1 : o1;
                c2 = fminf(fminf(c2, o2), keep);
                c1 = take ? o1 : c1;
                cix = take ? oi : cix;
            }
            if (quad == 0) {
                const int j = j0 + w * 64 + ct * 16 + l15;
                P[((size_t)batch * NS + (16 + b)) * NN + j] =
                    (float4){c1, __int_as_float(cix), c2, 0.f};
            }
        }
    }

    // ---- row-fold: per-row top-2 over the tile's 256 columns ----
    float m1[16], m2[16]; int i1[16];
    #pragma unroll
    for (int r = 0; r < 16; ++r) { m1[r] = FLT_MAX; m2[r] = FLT_MAX; i1[r] = 0x7fffffff; }

    #pragma unroll
    for (int ct = 0; ct < 4; ++ct) {
        const int col = j0 + w * 64 + ct * 16 + l15;
        const float dj = Dall[col];
        #pragma unroll
        for (int rt = 0; rt < 4; ++rt) {
            #pragma unroll
            for (int p = 0; p < 4; ++p) {
                const int rglob = i0 + rt * 16 + quad * 4 + p;
                float v = fmaf(-2.0f, acc[rt][ct][p], dj);
                v = (col == rglob) ? FLT_MAX : v;       // self only in diag jobs
                const int slot = rt * 4 + p;
                const bool lt = v < m1[slot];
                m2[slot] = fminf(m2[slot], fmaxf(m1[slot], v));
                m1[slot] = fminf(m1[slot], v);
                i1[slot] = lt ? col : i1[slot];
            }
        }
    }

    #pragma unroll
    for (int s = 0; s < 16; ++s) {
        float a1 = m1[s], a2 = m2[s]; int ai = i1[s];
        #pragma unroll
        for (int msk = 1; msk < 16; msk <<= 1) {
            const float o1 = __shfl_xor(a1, msk, 64);
            const float o2 = __shfl_xor(a2, msk, 64);
            const int   oi = __shfl_xor(ai, msk, 64);
            const bool take = (o1 < a1) || (o1 == a1 && oi < ai);
            const float keep = take ? a1 : o1;
            a2 = fminf(fminf(a2, o2), keep);
            a1 = take ? o1 : a1;
            ai = take ? oi : ai;
        }
        m1[s] = a1; m2[s] = a2; i1[s] = ai;
    }
    if (l15 == 0) {
        #pragma unroll
        for (int s = 0; s < 16; ++s) {
            const int rloc = (s >> 2) * 16 + quad * 4 + (s & 3);
            float* p = &Scr[(rloc * 4 + w) * 3];
            p[0] = m1[s]; p[1] = __int_as_float(i1[s]); p[2] = m2[s];
        }
    }
    __syncthreads();
    if (tid < TI) {
        float M1 = FLT_MAX, M2 = FLT_MAX; int I1 = 0x7fffffff;
        #pragma unroll
        for (int t = 0; t < 4; ++t) {
            const float* p = &Scr[(tid * 4 + t) * 3];
            const float o1 = p[0]; const int oi = __float_as_int(p[1]); const float o2 = p[2];
            const bool take = (o1 < M1) || (o1 == M1 && oi < I1);
            const float keep = take ? M1 : o1;
            M2 = fminf(fminf(M2, o2), keep);
            M1 = take ? o1 : M1;
            I1 = take ? oi : I1;
        }
        P[((size_t)batch * NS + jt) * NN + i0 + tid] =
            (float4){M1, __int_as_float(I1), M2, 0.f};
    }
}

// ---------------- reduce: merge 80 partial records per row -> outputs ----------------
__global__ __launch_bounds__(256) void fcm_reduce(const float4* __restrict__ P,
                                                  const float* __restrict__ diag,
                                                  float* __restrict__ out) {
    const int r     = blockIdx.x * 256 + threadIdx.x;   // 0..16383
    const int batch = r >> 12;
    const int j     = r & (NN - 1);
    float M1 = FLT_MAX, M2 = FLT_MAX; int I1 = 0x7fffffff;
    for (int s = 0; s < NS; ++s) {
        const float4 rec = P[((size_t)batch * NS + s) * NN + j];
        const float o1 = rec.x, o2 = rec.z;
        const int   oi = __float_as_int(rec.y);
        const bool take = (o1 < M1) || (o1 == M1 && oi < I1);
        const float keep = take ? M1 : o1;
        M2 = fminf(fminf(M2, o2), keep);
        M1 = take ? o1 : M1;
        I1 = take ? oi : I1;
    }
    const float di = diag[(size_t)batch * NN + j];
    const float d1 = sqrtf(fmaxf(di + M1, 0.0f) + 1e-9f);
    const float d2 = sqrtf(fmaxf(di + M2, 0.0f) + 1e-9f);
    const float e  = expf(d1);
    const float pred = (d1 / d2 < 0.6f) ? 2.0f / (1.0f + e)
                                        : 2.0f / (1.0f + 2.0f * e);
    out[(size_t)batch * NN + j] = pred;
    out[(size_t)NB * NN + (size_t)batch * NN + j] = (float)I1;
}

// ---------------- r8 full-matrix kernel (fallback if ws too small for partials) ----------------
__global__ __launch_bounds__(256, 1) void fcm_mfma(const f16* __restrict__ xh,
                                                   const f16* __restrict__ xl,
                                                   const float* __restrict__ diag,
                                                   float* __restrict__ out) {
    __shared__ f16 Ah[TI * NC];
    __shared__ f16 Al[TI * NC];
    __shared__ f16 Sh[2][4 * 2048];
    __shared__ f16 Sl[2][4 * 2048];
    __shared__ float Dall[NN];
    __shared__ float Scr[TI * 4 * 3];

    const int tid   = threadIdx.x;
    const int bx    = blockIdx.x;
    const int batch = (bx & 7) >> 1;
    const int band  = ((bx >> 3) << 1) | (bx & 1);
    const int i0    = band * TI;

    const f16* __restrict__ xhb = xh + (size_t)batch * NN * NC;
    const f16* __restrict__ xlb = xl + (size_t)batch * NN * NC;
    const float* __restrict__ db = diag + (size_t)batch * NN;

    const int w    = tid >> 6;
    const int lane = tid & 63;
    const int quad = lane >> 4;
    const int l15  = lane & 15;
    const int sw   = l15 & 7;

    {
        const int rsub = lane >> 5;
        const int s    = lane & 31;
        #pragma unroll
        for (int it = 0; it < 8; ++it) {
            const int t  = w * 8 + it;
            const int rg = t * 2 + rsub;
            const int g  = s ^ (rg & 7);
            const size_t goff = (size_t)(i0 + rg) * NC + g * 8;
            gl_lds16(xhb + goff, Ah + t * 512);
            gl_lds16(xlb + goff, Al + t * 512);
        }
    }
    #pragma unroll
    for (int t = 0; t < 4; ++t) {
        const int seg = (w * 4 + t) * 256;
        gl_lds16(db + seg + lane * 4, Dall + seg);
    }

    const int bcol  = lane >> 2;
    const int bslot = (lane & 3) ^ ((lane >> 3) & 3);
    const int gB    = (quad ^ ((l15 >> 1) & 3)) * 8;

    #pragma unroll
    for (int t = 0; t < 4; ++t) {
        const int col = w * 64 + t * 16 + bcol;
        gl_lds16(xhb + (size_t)col * NC + bslot * 8, &Sh[0][w * 2048] + t * 512);
        gl_lds16(xlb + (size_t)col * NC + bslot * 8, &Sl[0][w * 2048] + t * 512);
    }
    #pragma unroll
    for (int t = 0; t < 4; ++t) {
        const int col = w * 64 + t * 16 + bcol;
        gl_lds16(xhb + (size_t)col * NC + KCB + bslot * 8, &Sh[1][w * 2048] + t * 512);
        gl_lds16(xlb + (size_t)col * NC + KCB + bslot * 8, &Sl[1][w * 2048] + t * 512);
    }
    __syncthreads();

    f16x8 a0h, a0l, a1h, a1l, a2h, a2l, a3hA, a3lA, a3hB, a3lB;
    f16x8 bAh[4], bAl[4], bBh[4], bBl[4];

    #pragma unroll
    for (int ct = 0; ct < 4; ++ct) {
        const int c = ct * 16 + l15;
        bAh[ct] = *(const f16x8*)&Sh[0][w * 2048 + c * KCB + gB];
        bAl[ct] = *(const f16x8*)&Sl[0][w * 2048 + c * KCB + gB];
    }
    RDA(a0h, a0l, 0, 0) RDA(a1h, a1l, 1, 0) RDA(a2h, a2l, 2, 0) RDA(a3hA, a3lA, 3, 0)
    asm volatile("s_waitcnt lgkmcnt(0)" ::: "memory");
    SB;

    float m1[16], m2[16]; int i1[16];
    #pragma unroll
    for (int r = 0; r < 16; ++r) { m1[r] = FLT_MAX; m2[r] = FLT_MAX; i1[r] = 0x7fffffff; }

    for (int jt = 0; jt < NJT; ++jt) {
        f32x4 acc[4][4];
        #pragma unroll
        for (int rt = 0; rt < 4; ++rt)
            #pragma unroll
            for (int ct = 0; ct < 4; ++ct)
                acc[rt][ct] = (f32x4){0.f, 0.f, 0.f, 0.f};

        CHUNK(0, bAh, bAl, bBh, bBl, a3hA, a3lA, a3hB, a3lB);
        CHUNK(1, bBh, bBl, bAh, bAl, a3hB, a3lB, a3hA, a3lA);
        CHUNK(2, bAh, bAl, bBh, bBl, a3hA, a3lA, a3hB, a3lB);
        CHUNK(3, bBh, bBl, bAh, bAl, a3hB, a3lB, a3hA, a3lA);
        CHUNK(4, bAh, bAl, bBh, bBl, a3hA, a3lA, a3hB, a3lB);
        CHUNK(5, bBh, bBl, bAh, bAl, a3hB, a3lB, a3hA, a3lA);
        CHUNK(6, bAh, bAl, bBh, bBl, a3hA, a3lA, a3hB, a3lB);
        CHUNK(7, bBh, bBl, bAh, bAl, a3hB, a3lB, a3hA, a3lA);

        #pragma unroll
        for (int ct = 0; ct < 4; ++ct) {
            const int col = jt * TJ + w * 64 + ct * 16 + l15;
            const float dj = Dall[col];
            #pragma unroll
            for (int rt = 0; rt < 4; ++rt) {
                #pragma unroll
                for (int p = 0; p < 4; ++p) {
                    const int rglob = i0 + rt * 16 + quad * 4 + p;
                    float v = fmaf(-2.0f, acc[rt][ct][p], dj);
                    v = (col == rglob) ? FLT_MAX : v;
                    const int slot = rt * 4 + p;
                    const bool lt = v < m1[slot];
                    m2[slot] = fminf(m2[slot], fmaxf(m1[slot], v));
                    m1[slot] = fminf(m1[slot], v);
                    i1[slot] = lt ? col : i1[slot];
                }
            }
        }
    }

    #pragma unroll
    for (int s = 0; s < 16; ++s) {
        float a1 = m1[s], a2 = m2[s]; int ai = i1[s];
        #pragma unroll
        for (int msk = 1; msk < 16; msk <<= 1) {
            const float o1 = __shfl_xor(a1, msk, 64);
            const float o2 = __shfl_xor(a2, msk, 64);
            const int   oi = __shfl_xor(ai, msk, 64);
            const bool take = (o1 < a1) || (o1 == a1 && oi < ai);
            const float keep = take ? a1 : o1;
            a2 = fminf(fminf(a2, o2), keep);
            a1 = take ? o1 : a1;
            ai = take ? oi : ai;
        }
        m1[s] = a1; m2[s] = a2; i1[s] = ai;
    }
    if (l15 == 0) {
        #pragma unroll
        for (int s = 0; s < 16; ++s) {
            const int rloc = (s >> 2) * 16 + quad * 4 + (s & 3);
            float* p = &Scr[(rloc * 4 + w) * 3];
            p[0] = m1[s]; p[1] = __int_as_float(i1[s]); p[2] = m2[s];
        }
    }
    __syncthreads();
    if (tid < TI) {
        float M1 = FLT_MAX, M2 = FLT_MAX; int I1 = 0x7fffffff;
        #pragma unroll
        for (int t = 0; t < 4; ++t) {
            const float* p = &Scr[(tid * 4 + t) * 3];
            const float o1 = p[0]; const int oi = __float_as_int(p[1]); const float o2 = p[2];
            const bool take = (o1 < M1) || (o1 == M1 && oi < I1);
            const float keep = take ? M1 : o1;
            M2 = fminf(fminf(M2, o2), keep);
            M1 = take ? o1 : M1;
            I1 = take ? oi : I1;
        }
        const int   gi = i0 + tid;
        const float di = Dall[gi];
        const float d1 = sqrtf(fmaxf(di + M1, 0.0f) + 1e-9f);
        const float d2 = sqrtf(fmaxf(di + M2, 0.0f) + 1e-9f);
        const float e  = expf(d1);
        const float pred = (d1 / d2 < 0.6f) ? 2.0f / (1.0f + e)
                                            : 2.0f / (1.0f + 2.0f * e);
        out[(size_t)batch * NN + gi] = pred;
        out[(size_t)NB * NN + (size_t)batch * NN + gi] = (float)I1;
    }
}

// ---------------- fp32 fallback (round-1, passed) if ws too small ----------------
__global__ __launch_bounds__(256) void diag_kernel(const float* __restrict__ x,
                                                   float* __restrict__ diag) {
    const int lane = threadIdx.x & 63;
    const int wave = threadIdx.x >> 6;
    const int row  = (blockIdx.x << 2) + wave;
    const float4 v = ((const float4*)(x + (size_t)row * NC))[lane];
    float s = v.x * v.x + v.y * v.y + v.z * v.z + v.w * v.w;
    #pragma unroll
    for (int off = 32; off; off >>= 1) s += __shfl_xor(s, off, 64);
    if (lane == 0) diag[row] = s;
}

#define FTI 64
#define FTJ 256
#define FKC 16

__global__ __launch_bounds__(256) void fcm_fallback(const float* __restrict__ x,
                                                    const float* __restrict__ diag,
                                                    float* __restrict__ out) {
    __shared__ float As[FKC * FTI];
    __shared__ float Bs[FKC * FTJ];
    __shared__ float Dsf[FTJ];
    __shared__ float Scrf[FTI * 32 * 3];

    const int tid = threadIdx.x;
    const int bx  = blockIdx.x;
    const int batch = (bx & 7) >> 1;
    const int tile  = ((bx >> 3) << 1) | (bx & 1);
    const int i0    = tile * FTI;
    const float* __restrict__ xb = x + (size_t)batch * NN * NC;
    const float* __restrict__ db = diag + (size_t)batch * NN;
    const int tx = tid & 31;
    const int ty = tid >> 5;
    const int sr  = tid & 63;
    const int sk0 = (tid >> 6) << 2;

    float m1[8], m2[8]; int i1[8];
    #pragma unroll
    for (int r = 0; r < 8; ++r) { m1[r] = FLT_MAX; m2[r] = FLT_MAX; i1[r] = 0; }

    for (int jt = 0; jt < NN / FTJ; ++jt) {
        const int j0 = jt * FTJ;
        __syncthreads();
        Dsf[tid] = db[j0 + tid];
        float acc[8][8];
        #pragma unroll
        for (int r = 0; r < 8; ++r)
            #pragma unroll
            for (int c = 0; c < 8; ++c) acc[r][c] = 0.0f;
        float4 pa  = *(const float4*)(xb + (size_t)(i0 + sr) * NC + sk0);
        const float* bsrc = xb + (size_t)(j0 + tid) * NC;
        float4 pb0 = *(const float4*)(bsrc + 0);
        float4 pb1 = *(const float4*)(bsrc + 4);
        float4 pb2 = *(const float4*)(bsrc + 8);
        float4 pb3 = *(const float4*)(bsrc + 12);
        for (int kc = 0; kc < NC / FKC; ++kc) {
            __syncthreads();
            As[(sk0 + 0) * FTI + sr] = pa.x;
            As[(sk0 + 1) * FTI + sr] = pa.y;
            As[(sk0 + 2) * FTI + sr] = pa.z;
            As[(sk0 + 3) * FTI + sr] = pa.w;
            Bs[ 0 * FTJ + tid] = pb0.x; Bs[ 1 * FTJ + tid] = pb0.y;
            Bs[ 2 * FTJ + tid] = pb0.z; Bs[ 3 * FTJ + tid] = pb0.w;
            Bs[ 4 * FTJ + tid] = pb1.x; Bs[ 5 * FTJ + tid] = pb1.y;
            Bs[ 6 * FTJ + tid] = pb1.z; Bs[ 7 * FTJ + tid] = pb1.w;
            Bs[ 8 * FTJ + tid] = pb2.x; Bs[ 9 * FTJ + tid] = pb2.y;
            Bs[10 * FTJ + tid] = pb2.z; Bs[11 * FTJ + tid] = pb2.w;
            Bs[12 * FTJ + tid] = pb3.x; Bs[13 * FTJ + tid] = pb3.y;
            Bs[14 * FTJ + tid] = pb3.z; Bs[15 * FTJ + tid] = pb3.w;
            if (kc + 1 < NC / FKC) {
                const int kb = (kc + 1) * FKC;
                pa  = *(const float4*)(xb + (size_t)(i0 + sr) * NC + kb + sk0);
                pb0 = *(const float4*)(bsrc + kb + 0);
                pb1 = *(const float4*)(bsrc + kb + 4);
                pb2 = *(const float4*)(bsrc + kb + 8);
                pb3 = *(const float4*)(bsrc + kb + 12);
            }
            __syncthreads();
            #pragma unroll
            for (int k = 0; k < FKC; ++k) {
                float av[8], bv[8];
                *(float4*)&av[0] = *(const float4*)&As[k * FTI + ty * 8];
                *(float4*)&av[4] = *(const float4*)&As[k * FTI + ty * 8 + 4];
                *(float4*)&bv[0] = *(const float4*)&Bs[k * FTJ + tx * 8];
                *(float4*)&bv[4] = *(const float4*)&Bs[k * FTJ + tx * 8 + 4];
                #pragma unroll
                for (int r = 0; r < 8; ++r)
                    #pragma unroll
                    for (int c = 0; c < 8; ++c)
                        acc[r][c] = fmaf(av[r], bv[c], acc[r][c]);
            }
        }
        #pragma unroll
        for (int c = 0; c < 8; ++c) {
            const int j = j0 + tx * 8 + c;
            const float dj = Dsf[tx * 8 + c];
            #pragma unroll
            for (int r = 0; r < 8; ++r) {
                const int ig = i0 + ty * 8 + r;
                float v = fmaf(-2.0f, acc[r][c], dj);
                v = (j == ig) ? FLT_MAX : v;
                const bool lt = v < m1[r];
                m2[r] = fminf(m2[r], fmaxf(m1[r], v));
                m1[r] = fminf(m1[r], v);
                i1[r] = lt ? j : i1[r];
            }
        }
    }
    __syncthreads();
    #pragma unroll
    for (int r = 0; r < 8; ++r) {
        float* s = &Scrf[((ty * 8 + r) * 32 + tx) * 3];
        s[0] = m1[r]; s[1] = __int_as_float(i1[r]); s[2] = m2[r];
    }
    __syncthreads();
    if (tid < FTI) {
        float M1 = FLT_MAX, M2 = FLT_MAX; int I1 = 0;
        for (int t = 0; t < 32; ++t) {
            const float* s = &Scrf[(tid * 32 + t) * 3];
            const float v1 = s[0]; const int ii = __float_as_int(s[1]);
            const float v2 = s[2];
            if (v1 < M1 || (v1 == M1 && ii < I1)) {
                M2 = fminf(M2, M1); M1 = v1; I1 = ii;
            } else {
                M2 = fminf(M2, v1);
            }
            M2 = fminf(M2, v2);
        }
        const int   gi = i0 + tid;
        const float di = db[gi];
        const float d1 = sqrtf(fmaxf(di + M1, 0.0f) + 1e-9f);
        const float d2 = sqrtf(fmaxf(di + M2, 0.0f) + 1e-9f);
        const float e  = expf(d1);
        const float pred = (d1 / d2 < 0.6f) ? 2.0f / (1.0f + e)
                                            : 2.0f / (1.0f + 2.0f * e);
        out[(size_t)batch * NN + gi] = pred;
        out[(size_t)NB * NN + (size_t)batch * NN + gi] = (float)I1;
    }
}

extern "C" void kernel_launch(void* const* d_in, const int* in_sizes, int n_in,
                              void* d_out, int out_size, void* d_ws, size_t ws_size,
                              hipStream_t stream) {
    const float* x = (const float*)d_in[0];
    float* out     = (float*)d_out;
    const size_t n_elem    = (size_t)NB * NN * NC;
    const size_t need      = n_elem * 2 * 2 + (size_t)NB * NN * 4;   // f16 hi/lo + diag
    const size_t part_b    = (size_t)NB * NS * NN * 16;              // partials (21 MB)
    const size_t need_sym  = need + part_b;
    if (ws_size >= need_sym) {
        f16*    xh   = (f16*)d_ws;
        f16*    xl   = xh + n_elem;
        float*  diag = (float*)(xl + n_elem);
        float4* P    = (float4*)((char*)d_ws + need);                // 16B-aligned
        prep_kernel<<<dim3(NB * NN / 4), dim3(256), 0, stream>>>(x, xh, xl, diag);
        hipMemsetAsync(P, 0x7f, part_b, stream);                     // huge-sentinel init
        fcm_sym<<<dim3(NB * NJOBS), dim3(256), 0, stream>>>(xh, xl, diag, P);
        fcm_reduce<<<dim3(NB * NN / 256), dim3(256), 0, stream>>>(P, diag, out);
    } else if (ws_size >= need) {
        f16*   xh   = (f16*)d_ws;
        f16*   xl   = xh + n_elem;
        float* diag = (float*)(xl + n_elem);
        prep_kernel<<<dim3(NB * NN / 4), dim3(256), 0, stream>>>(x, xh, xl, diag);
        fcm_mfma<<<dim3(256), dim3(256), 0, stream>>>(xh, xl, diag, out);
    } else {
        float* diag = (float*)d_ws;
        diag_kernel<<<dim3(NB * NN / 4), dim3(256), 0, stream>>>(x, diag);
        fcm_fallback<<<dim3(256), dim3(256), 0, stream>>>(x, diag, out);
    }
}

// Round 16
// 220.483 us; speedup vs baseline: 1.0317x; 1.0317x over previous
//
#include <hip/hip_runtime.h>
#include <cfloat>

#define NB 4
#define NN 4096
#define NC 256

typedef _Float16 f16;
typedef _Float16 f16x8 __attribute__((ext_vector_type(8)));
typedef float f32x4 __attribute__((ext_vector_type(4)));

__device__ __forceinline__ void gl_lds16(const void* g, void* l) {
    __builtin_amdgcn_global_load_lds(
        (const __attribute__((address_space(1))) unsigned int*)g,
        (__attribute__((address_space(3))) unsigned int*)l, 16, 0, 0);
}

// ---------------- prep: fp32 -> f16 hi/lo split + diag ----------------
__global__ __launch_bounds__(256) void prep_kernel(const float* __restrict__ x,
                                                   f16* __restrict__ xh,
                                                   f16* __restrict__ xl,
                                                   float* __restrict__ diag) {
    const int lane = threadIdx.x & 63;
    const int wave = threadIdx.x >> 6;
    const int row  = (blockIdx.x << 2) + wave;            // 0..16383
    const float4 v = ((const float4*)(x + (size_t)row * NC))[lane];
    union { f16 h[4]; uint2 u; } H, L;
    float vv[4] = {v.x, v.y, v.z, v.w};
    float s = 0.f;
    #pragma unroll
    for (int k = 0; k < 4; ++k) {
        H.h[k] = (f16)vv[k];
        L.h[k] = (f16)(vv[k] - (float)H.h[k]);
        s = fmaf(vv[k], vv[k], s);
    }
    *(uint2*)(xh + (size_t)row * NC + lane * 4) = H.u;
    *(uint2*)(xl + (size_t)row * NC + lane * 4) = L.u;
    #pragma unroll
    for (int off = 32; off; off >>= 1) s += __shfl_xor(s, off, 64);
    if (lane == 0) diag[row] = s;
}

// ---------------- shared tile machinery (r8, verified) ----------------
#define TI 64
#define TJ 256
#define KCB 32
#define NCHUNK (NC / KCB)    // 8 k-chunks per j-tile
#define NJT (NN / TJ)        // 16 j-tiles
#define NJOBS 544            // 64 diagonal + 480 upper (triangular) jobs/batch
#define NS 80                // partial slots/row: 16 row-slots + 64 col-slots

#define TRIPLE(RT, CT, AH, AL, BH, BL) \
    acc[RT][CT] = __builtin_amdgcn_mfma_f32_16x16x32_f16(AH, BH[CT], acc[RT][CT], 0, 0, 0); \
    acc[RT][CT] = __builtin_amdgcn_mfma_f32_16x16x32_f16(AH, BL[CT], acc[RT][CT], 0, 0, 0); \
    acc[RT][CT] = __builtin_amdgcn_mfma_f32_16x16x32_f16(AL, BH[CT], acc[RT][CT], 0, 0, 0);

#define QUARTER(RT, AH, AL, BH, BL) \
    TRIPLE(RT, 0, AH, AL, BH, BL) TRIPLE(RT, 1, AH, AL, BH, BL) \
    TRIPLE(RT, 2, AH, AL, BH, BL) TRIPLE(RT, 3, AH, AL, BH, BL)

#define RDA(DH, DL, RT, KN) \
    DH = *(const f16x8*)&Ah[((RT) * 16 + l15) * NC + ((((KN) * 4 + quad) ^ sw) * 8)]; \
    DL = *(const f16x8*)&Al[((RT) * 16 + l15) * NC + ((((KN) * 4 + quad) ^ sw) * 8)];

#define SB __builtin_amdgcn_sched_barrier(0)

// r8 CHUNK (multi-tile loop version, used by fcm_mfma fallback path)
#define CHUNK(KC, BHC, BLC, BHN, BLN, A3HC, A3LC, A3HN, A3LN) do { \
    asm volatile("s_waitcnt lgkmcnt(0)" ::: "memory"); \
    SB; \
    { \
        int jn = jt + (((KC) + 2) >> 3); if (jn >= NJT) jn = 0; \
        const int kn = ((KC) + 2) & 7; \
        f16* const dh = &Sh[(KC) & 1][w * 2048]; \
        f16* const dl = &Sl[(KC) & 1][w * 2048]; \
        _Pragma("unroll") \
        for (int t = 0; t < 4; ++t) { \
            const int col = jn * TJ + w * 64 + t * 16 + bcol; \
            const size_t goff = (size_t)col * NC + (size_t)(kn * KCB) + bslot * 8; \
            gl_lds16(xhb + goff, dh + t * 512); \
            gl_lds16(xlb + goff, dl + t * 512); \
        } \
    } \
    SB; \
    QUARTER(0, a0h, a0l, BHC, BLC) \
    RDA(a0h, a0l, 0, ((KC) + 1) & 7) \
    SB; \
    QUARTER(1, a1h, a1l, BHC, BLC) \
    RDA(a1h, a1l, 1, ((KC) + 1) & 7) \
    SB; \
    QUARTER(2, a2h, a2l, BHC, BLC) \
    asm volatile("s_waitcnt vmcnt(8)" ::: "memory"); \
    SB; \
    { \
        const f16* const rh = &Sh[((KC) + 1) & 1][w * 2048]; \
        const f16* const rl = &Sl[((KC) + 1) & 1][w * 2048]; \
        _Pragma("unroll") \
        for (int ct = 0; ct < 4; ++ct) { \
            const int c = ct * 16 + l15; \
            BHN[ct] = *(const f16x8*)&rh[c * KCB + gB]; \
            BLN[ct] = *(const f16x8*)&rl[c * KCB + gB]; \
        } \
    } \
    RDA(a2h, a2l, 2, ((KC) + 1) & 7) \
    RDA(A3HN, A3LN, 3, ((KC) + 1) & 7) \
    SB; \
    QUARTER(3, A3HC, A3LC, BHC, BLC) \
} while (0)

// single-tile CHUNK for symmetric jobs: jt fixed, prefetch wraps kn in-tile.
// NOTE: chunks 6/7 re-stage kn 0/1 (idempotent, reads discarded) — keeps the
// 8-issues-per-chunk invariant the vmcnt(8) count depends on. Do not guard.
#define CHUNK2(KC, BHC, BLC, BHN, BLN, A3HC, A3LC, A3HN, A3LN) do { \
    asm volatile("s_waitcnt lgkmcnt(0)" ::: "memory"); \
    SB; \
    { \
        const int kn = ((KC) + 2) & 7; \
        f16* const dh = &Sh[(KC) & 1][w * 2048]; \
        f16* const dl = &Sl[(KC) & 1][w * 2048]; \
        _Pragma("unroll") \
        for (int t = 0; t < 4; ++t) { \
            const int col = j0 + w * 64 + t * 16 + bcol; \
            const size_t goff = (size_t)col * NC + (size_t)(kn * KCB) + bslot * 8; \
            gl_lds16(xhb + goff, dh + t * 512); \
            gl_lds16(xlb + goff, dl + t * 512); \
        } \
    } \
    SB; \
    QUARTER(0, a0h, a0l, BHC, BLC) \
    RDA(a0h, a0l, 0, ((KC) + 1) & 7) \
    SB; \
    QUARTER(1, a1h, a1l, BHC, BLC) \
    RDA(a1h, a1l, 1, ((KC) + 1) & 7) \
    SB; \
    QUARTER(2, a2h, a2l, BHC, BLC) \
    asm volatile("s_waitcnt vmcnt(8)" ::: "memory"); \
    SB; \
    { \
        const f16* const rh = &Sh[((KC) + 1) & 1][w * 2048]; \
        const f16* const rl = &Sl[((KC) + 1) & 1][w * 2048]; \
        _Pragma("unroll") \
        for (int ct = 0; ct < 4; ++ct) { \
            const int c = ct * 16 + l15; \
            BHN[ct] = *(const f16x8*)&rh[c * KCB + gB]; \
            BLN[ct] = *(const f16x8*)&rl[c * KCB + gB]; \
        } \
    } \
    RDA(a2h, a2l, 2, ((KC) + 1) & 7) \
    RDA(A3HN, A3LN, 3, ((KC) + 1) & 7) \
    SB; \
    QUARTER(3, A3HC, A3LC, BHC, BLC) \
} while (0)

// ---------------- symmetric job kernel (r16: jt-major order, no Dall) ----------------
// Same job SET as r15 (verified correct); only the ENUMERATION changed:
// per batch, tile jt owns 4jt+4 jobs (4 diagonal bands 4jt..4jt+3, then the
// 4jt upper bands 0..4jt-1). With bx = job*4 + batch, XCD k (bx mod 8) gets
// a FIXED batch and consecutive same-jt jobs -> the 512KB B tile + 16KB diag
// stay hot in that XCD's L2 (r15's scattered order streamed ~870MB from L3:
// MfmaUtil 12%, 49K cyc/job). Dall LDS stage dropped; folds read db[] direct.
__global__ __launch_bounds__(256, 1) void fcm_sym(const f16* __restrict__ xh,
                                                  const f16* __restrict__ xl,
                                                  const float* __restrict__ diag,
                                                  float4* __restrict__ P) {
    __shared__ f16 Ah[TI * NC];          // 32 KB  persistent A hi (swizzled)
    __shared__ f16 Al[TI * NC];          // 32 KB  persistent A lo
    __shared__ f16 Sh[2][4 * 2048];      // 32 KB  B hi stripes, double-buffered
    __shared__ f16 Sl[2][4 * 2048];      // 32 KB  B lo stripes, double-buffered
    __shared__ float Scr[TI * 4 * 3];    // 3 KB   cross-wave merge

    const int tid   = threadIdx.x;
    const int bx    = blockIdx.x;
    const int batch = bx & 3;            // period-8 alias -> fixed batch per XCD

    // jt-major decode: cumulative jobs before tile jt = 2jt^2+2jt
    int u = bx >> 2;                     // 0..543
    int jt = 0;
    while (u >= 4 * jt + 4) { u -= 4 * jt + 4; ++jt; }
    const bool isDiag = (u < 4);
    const int b  = isDiag ? (4 * jt + u) : (u - 4);
    const int i0 = b * TI;
    const int j0 = jt * TJ;

    const f16* __restrict__ xhb = xh + (size_t)batch * NN * NC;
    const f16* __restrict__ xlb = xl + (size_t)batch * NN * NC;
    const float* __restrict__ db = diag + (size_t)batch * NN;

    const int w    = tid >> 6;    // 0..3
    const int lane = tid & 63;
    const int quad = lane >> 4;
    const int l15  = lane & 15;
    const int sw   = l15 & 7;

    // ---- A stage (once): LDS[row][granule ^ (row&7)] ----
    {
        const int rsub = lane >> 5;
        const int s    = lane & 31;
        #pragma unroll
        for (int it = 0; it < 8; ++it) {
            const int t  = w * 8 + it;
            const int rg = t * 2 + rsub;
            const int g  = s ^ (rg & 7);
            const size_t goff = (size_t)(i0 + rg) * NC + g * 8;
            gl_lds16(xhb + goff, Ah + t * 512);
            gl_lds16(xlb + goff, Al + t * 512);
        }
    }

    const int bcol  = lane >> 2;
    const int bslot = (lane & 3) ^ ((lane >> 3) & 3);
    const int gB    = (quad ^ ((l15 >> 1) & 3)) * 8;

    // ---- prologue: stage chunk 0 -> buf0, chunk 1 -> buf1 (tile jt) ----
    #pragma unroll
    for (int t = 0; t < 4; ++t) {
        const int col = j0 + w * 64 + t * 16 + bcol;
        gl_lds16(xhb + (size_t)col * NC + bslot * 8, &Sh[0][w * 2048] + t * 512);
        gl_lds16(xlb + (size_t)col * NC + bslot * 8, &Sl[0][w * 2048] + t * 512);
    }
    #pragma unroll
    for (int t = 0; t < 4; ++t) {
        const int col = j0 + w * 64 + t * 16 + bcol;
        gl_lds16(xhb + (size_t)col * NC + KCB + bslot * 8, &Sh[1][w * 2048] + t * 512);
        gl_lds16(xlb + (size_t)col * NC + KCB + bslot * 8, &Sl[1][w * 2048] + t * 512);
    }
    __syncthreads();

    f16x8 a0h, a0l, a1h, a1l, a2h, a2l, a3hA, a3lA, a3hB, a3lB;
    f16x8 bAh[4], bAl[4], bBh[4], bBl[4];

    #pragma unroll
    for (int ct = 0; ct < 4; ++ct) {
        const int c = ct * 16 + l15;
        bAh[ct] = *(const f16x8*)&Sh[0][w * 2048 + c * KCB + gB];
        bAl[ct] = *(const f16x8*)&Sl[0][w * 2048 + c * KCB + gB];
    }
    RDA(a0h, a0l, 0, 0) RDA(a1h, a1l, 1, 0) RDA(a2h, a2l, 2, 0) RDA(a3hA, a3lA, 3, 0)
    asm volatile("s_waitcnt lgkmcnt(0)" ::: "memory");
    SB;

    f32x4 acc[4][4];
    #pragma unroll
    for (int rt = 0; rt < 4; ++rt)
        #pragma unroll
        for (int ct = 0; ct < 4; ++ct)
            acc[rt][ct] = (f32x4){0.f, 0.f, 0.f, 0.f};

    CHUNK2(0, bAh, bAl, bBh, bBl, a3hA, a3lA, a3hB, a3lB);
    CHUNK2(1, bBh, bBl, bAh, bAl, a3hB, a3lB, a3hA, a3lA);
    CHUNK2(2, bAh, bAl, bBh, bBl, a3hA, a3lA, a3hB, a3lB);
    CHUNK2(3, bBh, bBl, bAh, bAl, a3hB, a3lB, a3hA, a3lA);
    CHUNK2(4, bAh, bAl, bBh, bBl, a3hA, a3lA, a3hB, a3lB);
    CHUNK2(5, bBh, bBl, bAh, bAl, a3hB, a3lB, a3hA, a3lA);
    CHUNK2(6, bAh, bAl, bBh, bBl, a3hA, a3lA, a3hB, a3lB);
    CHUNK2(7, bBh, bBl, bAh, bAl, a3hB, a3lB, a3hA, a3lA);

    // ---- column-fold (upper jobs only): per-column top-2 over band b rows ----
    if (!isDiag) {
        float dro[16];
        #pragma unroll
        for (int s = 0; s < 16; ++s)
            dro[s] = db[i0 + (s >> 2) * 16 + quad * 4 + (s & 3)];   // L2-hot
        #pragma unroll
        for (int ct = 0; ct < 4; ++ct) {
            float c1 = FLT_MAX, c2 = FLT_MAX; int cix = 0x7fffffff;
            #pragma unroll
            for (int s = 0; s < 16; ++s) {             // increasing i order
                const int ii = i0 + (s >> 2) * 16 + quad * 4 + (s & 3);
                const float v = fmaf(-2.0f, acc[s >> 2][ct][s & 3], dro[s]);
                const bool lt = v < c1;
                c2 = fminf(c2, fmaxf(c1, v));
                c1 = fminf(c1, v);
                cix = lt ? ii : cix;
            }
            #pragma unroll
            for (int msk = 16; msk < 64; msk <<= 1) {  // merge across quads
                const float o1 = __shfl_xor(c1, msk, 64);
                const float o2 = __shfl_xor(c2, msk, 64);
                const int   oi = __shfl_xor(cix, msk, 64);
                const bool take = (o1 < c1) || (o1 == c1 && oi < cix);
                const float keep = take ? c1 : o1;
                c2 = fminf(fminf(c2, o2), keep);
                c1 = take ? o1 : c1;
                cix = take ? oi : cix;
            }
            if (quad == 0) {
                const int j = j0 + w * 64 + ct * 16 + l15;
                P[((size_t)batch * NS + (16 + b)) * NN + j] =
                    (float4){c1, __int_as_float(cix), c2, 0.f};
            }
        }
    }

    // ---- row-fold: per-row top-2 over the tile's 256 columns ----
    float m1[16], m2[16]; int i1[16];
    #pragma unroll
    for (int r = 0; r < 16; ++r) { m1[r] = FLT_MAX; m2[r] = FLT_MAX; i1[r] = 0x7fffffff; }

    #pragma unroll
    for (int ct = 0; ct < 4; ++ct) {
        const int col = j0 + w * 64 + ct * 16 + l15;
        const float dj = db[col];                      // L2-hot
        #pragma unroll
        for (int rt = 0; rt < 4; ++rt) {
            #pragma unroll
            for (int p = 0; p < 4; ++p) {
                const int rglob = i0 + rt * 16 + quad * 4 + p;
                float v = fmaf(-2.0f, acc[rt][ct][p], dj);
                v = (col == rglob) ? FLT_MAX : v;       // self only in diag jobs
                const int slot = rt * 4 + p;
                const bool lt = v < m1[slot];
                m2[slot] = fminf(m2[slot], fmaxf(m1[slot], v));
                m1[slot] = fminf(m1[slot], v);
                i1[slot] = lt ? col : i1[slot];
            }
        }
    }

    #pragma unroll
    for (int s = 0; s < 16; ++s) {
        float a1 = m1[s], a2 = m2[s]; int ai = i1[s];
        #pragma unroll
        for (int msk = 1; msk < 16; msk <<= 1) {
            const float o1 = __shfl_xor(a1, msk, 64);
            const float o2 = __shfl_xor(a2, msk, 64);
            const int   oi = __shfl_xor(ai, msk, 64);
            const bool take = (o1 < a1) || (o1 == a1 && oi < ai);
            const float keep = take ? a1 : o1;
            a2 = fminf(fminf(a2, o2), keep);
            a1 = take ? o1 : a1;
            ai = take ? oi : ai;
        }
        m1[s] = a1; m2[s] = a2; i1[s] = ai;
    }
    if (l15 == 0) {
        #pragma unroll
        for (int s = 0; s < 16; ++s) {
            const int rloc = (s >> 2) * 16 + quad * 4 + (s & 3);
            float* p = &Scr[(rloc * 4 + w) * 3];
            p[0] = m1[s]; p[1] = __int_as_float(i1[s]); p[2] = m2[s];
        }
    }
    __syncthreads();
    if (tid < TI) {
        float M1 = FLT_MAX, M2 = FLT_MAX; int I1 = 0x7fffffff;
        #pragma unroll
        for (int t = 0; t < 4; ++t) {
            const float* p = &Scr[(tid * 4 + t) * 3];
            const float o1 = p[0]; const int oi = __float_as_int(p[1]); const float o2 = p[2];
            const bool take = (o1 < M1) || (o1 == M1 && oi < I1);
            const float keep = take ? M1 : o1;
            M2 = fminf(fminf(M2, o2), keep);
            M1 = take ? o1 : M1;
            I1 = take ? oi : I1;
        }
        P[((size_t)batch * NS + jt) * NN + i0 + tid] =
            (float4){M1, __int_as_float(I1), M2, 0.f};
    }
}

// ---------------- reduce: merge 80 partial records per row -> outputs ----------------
__global__ __launch_bounds__(256) void fcm_reduce(const float4* __restrict__ P,
                                                  const float* __restrict__ diag,
                                                  float* __restrict__ out) {
    const int r     = blockIdx.x * 256 + threadIdx.x;   // 0..16383
    const int batch = r >> 12;
    const int j     = r & (NN - 1);
    float M1 = FLT_MAX, M2 = FLT_MAX; int I1 = 0x7fffffff;
    for (int s = 0; s < NS; ++s) {
        const float4 rec = P[((size_t)batch * NS + s) * NN + j];
        const float o1 = rec.x, o2 = rec.z;
        const int   oi = __float_as_int(rec.y);
        const bool take = (o1 < M1) || (o1 == M1 && oi < I1);
        const float keep = take ? M1 : o1;
        M2 = fminf(fminf(M2, o2), keep);
        M1 = take ? o1 : M1;
        I1 = take ? oi : I1;
    }
    const float di = diag[(size_t)batch * NN + j];
    const float d1 = sqrtf(fmaxf(di + M1, 0.0f) + 1e-9f);
    const float d2 = sqrtf(fmaxf(di + M2, 0.0f) + 1e-9f);
    const float e  = expf(d1);
    const float pred = (d1 / d2 < 0.6f) ? 2.0f / (1.0f + e)
                                        : 2.0f / (1.0f + 2.0f * e);
    out[(size_t)batch * NN + j] = pred;
    out[(size_t)NB * NN + (size_t)batch * NN + j] = (float)I1;
}

// ---------------- r8 full-matrix kernel (fallback if ws too small for partials) ----------------
__global__ __launch_bounds__(256, 1) void fcm_mfma(const f16* __restrict__ xh,
                                                   const f16* __restrict__ xl,
                                                   const float* __restrict__ diag,
                                                   float* __restrict__ out) {
    __shared__ f16 Ah[TI * NC];
    __shared__ f16 Al[TI * NC];
    __shared__ f16 Sh[2][4 * 2048];
    __shared__ f16 Sl[2][4 * 2048];
    __shared__ float Dall[NN];
    __shared__ float Scr[TI * 4 * 3];

    const int tid   = threadIdx.x;
    const int bx    = blockIdx.x;
    const int batch = (bx & 7) >> 1;
    const int band  = ((bx >> 3) << 1) | (bx & 1);
    const int i0    = band * TI;

    const f16* __restrict__ xhb = xh + (size_t)batch * NN * NC;
    const f16* __restrict__ xlb = xl + (size_t)batch * NN * NC;
    const float* __restrict__ db = diag + (size_t)batch * NN;

    const int w    = tid >> 6;
    const int lane = tid & 63;
    const int quad = lane >> 4;
    const int l15  = lane & 15;
    const int sw   = l15 & 7;

    {
        const int rsub = lane >> 5;
        const int s    = lane & 31;
        #pragma unroll
        for (int it = 0; it < 8; ++it) {
            const int t  = w * 8 + it;
            const int rg = t * 2 + rsub;
            const int g  = s ^ (rg & 7);
            const size_t goff = (size_t)(i0 + rg) * NC + g * 8;
            gl_lds16(xhb + goff, Ah + t * 512);
            gl_lds16(xlb + goff, Al + t * 512);
        }
    }
    #pragma unroll
    for (int t = 0; t < 4; ++t) {
        const int seg = (w * 4 + t) * 256;
        gl_lds16(db + seg + lane * 4, Dall + seg);
    }

    const int bcol  = lane >> 2;
    const int bslot = (lane & 3) ^ ((lane >> 3) & 3);
    const int gB    = (quad ^ ((l15 >> 1) & 3)) * 8;

    #pragma unroll
    for (int t = 0; t < 4; ++t) {
        const int col = w * 64 + t * 16 + bcol;
        gl_lds16(xhb + (size_t)col * NC + bslot * 8, &Sh[0][w * 2048] + t * 512);
        gl_lds16(xlb + (size_t)col * NC + bslot * 8, &Sl[0][w * 2048] + t * 512);
    }
    #pragma unroll
    for (int t = 0; t < 4; ++t) {
        const int col = w * 64 + t * 16 + bcol;
        gl_lds16(xhb + (size_t)col * NC + KCB + bslot * 8, &Sh[1][w * 2048] + t * 512);
        gl_lds16(xlb + (size_t)col * NC + KCB + bslot * 8, &Sl[1][w * 2048] + t * 512);
    }
    __syncthreads();

    f16x8 a0h, a0l, a1h, a1l, a2h, a2l, a3hA, a3lA, a3hB, a3lB;
    f16x8 bAh[4], bAl[4], bBh[4], bBl[4];

    #pragma unroll
    for (int ct = 0; ct < 4; ++ct) {
        const int c = ct * 16 + l15;
        bAh[ct] = *(const f16x8*)&Sh[0][w * 2048 + c * KCB + gB];
        bAl[ct] = *(const f16x8*)&Sl[0][w * 2048 + c * KCB + gB];
    }
    RDA(a0h, a0l, 0, 0) RDA(a1h, a1l, 1, 0) RDA(a2h, a2l, 2, 0) RDA(a3hA, a3lA, 3, 0)
    asm volatile("s_waitcnt lgkmcnt(0)" ::: "memory");
    SB;

    float m1[16], m2[16]; int i1[16];
    #pragma unroll
    for (int r = 0; r < 16; ++r) { m1[r] = FLT_MAX; m2[r] = FLT_MAX; i1[r] = 0x7fffffff; }

    for (int jt = 0; jt < NJT; ++jt) {
        f32x4 acc[4][4];
        #pragma unroll
        for (int rt = 0; rt < 4; ++rt)
            #pragma unroll
            for (int ct = 0; ct < 4; ++ct)
                acc[rt][ct] = (f32x4){0.f, 0.f, 0.f, 0.f};

        CHUNK(0, bAh, bAl, bBh, bBl, a3hA, a3lA, a3hB, a3lB);
        CHUNK(1, bBh, bBl, bAh, bAl, a3hB, a3lB, a3hA, a3lA);
        CHUNK(2, bAh, bAl, bBh, bBl, a3hA, a3lA, a3hB, a3lB);
        CHUNK(3, bBh, bBl, bAh, bAl, a3hB, a3lB, a3hA, a3lA);
        CHUNK(4, bAh, bAl, bBh, bBl, a3hA, a3lA, a3hB, a3lB);
        CHUNK(5, bBh, bBl, bAh, bAl, a3hB, a3lB, a3hA, a3lA);
        CHUNK(6, bAh, bAl, bBh, bBl, a3hA, a3lA, a3hB, a3lB);
        CHUNK(7, bBh, bBl, bAh, bAl, a3hB, a3lB, a3hA, a3lA);

        #pragma unroll
        for (int ct = 0; ct < 4; ++ct) {
            const int col = jt * TJ + w * 64 + ct * 16 + l15;
            const float dj = Dall[col];
            #pragma unroll
            for (int rt = 0; rt < 4; ++rt) {
                #pragma unroll
                for (int p = 0; p < 4; ++p) {
                    const int rglob = i0 + rt * 16 + quad * 4 + p;
                    float v = fmaf(-2.0f, acc[rt][ct][p], dj);
                    v = (col == rglob) ? FLT_MAX : v;
                    const int slot = rt * 4 + p;
                    const bool lt = v < m1[slot];
                    m2[slot] = fminf(m2[slot], fmaxf(m1[slot], v));
                    m1[slot] = fminf(m1[slot], v);
                    i1[slot] = lt ? col : i1[slot];
                }
            }
        }
    }

    #pragma unroll
    for (int s = 0; s < 16; ++s) {
        float a1 = m1[s], a2 = m2[s]; int ai = i1[s];
        #pragma unroll
        for (int msk = 1; msk < 16; msk <<= 1) {
            const float o1 = __shfl_xor(a1, msk, 64);
            const float o2 = __shfl_xor(a2, msk, 64);
            const int   oi = __shfl_xor(ai, msk, 64);
            const bool take = (o1 < a1) || (o1 == a1 && oi < ai);
            const float keep = take ? a1 : o1;
            a2 = fminf(fminf(a2, o2), keep);
            a1 = take ? o1 : a1;
            ai = take ? oi : ai;
        }
        m1[s] = a1; m2[s] = a2; i1[s] = ai;
    }
    if (l15 == 0) {
        #pragma unroll
        for (int s = 0; s < 16; ++s) {
            const int rloc = (s >> 2) * 16 + quad * 4 + (s & 3);
            float* p = &Scr[(rloc * 4 + w) * 3];
            p[0] = m1[s]; p[1] = __int_as_float(i1[s]); p[2] = m2[s];
        }
    }
    __syncthreads();
    if (tid < TI) {
        float M1 = FLT_MAX, M2 = FLT_MAX; int I1 = 0x7fffffff;
        #pragma unroll
        for (int t = 0; t < 4; ++t) {
            const float* p = &Scr[(tid * 4 + t) * 3];
            const float o1 = p[0]; const int oi = __float_as_int(p[1]); const float o2 = p[2];
            const bool take = (o1 < M1) || (o1 == M1 && oi < I1);
            const float keep = take ? M1 : o1;
            M2 = fminf(fminf(M2, o2), keep);
            M1 = take ? o1 : M1;
            I1 = take ? oi : I1;
        }
        const int   gi = i0 + tid;
        const float di = Dall[gi];
        const float d1 = sqrtf(fmaxf(di + M1, 0.0f) + 1e-9f);
        const float d2 = sqrtf(fmaxf(di + M2, 0.0f) + 1e-9f);
        const float e  = expf(d1);
        const float pred = (d1 / d2 < 0.6f) ? 2.0f / (1.0f + e)
                                            : 2.0f / (1.0f + 2.0f * e);
        out[(size_t)batch * NN + gi] = pred;
        out[(size_t)NB * NN + (size_t)batch * NN + gi] = (float)I1;
    }
}

// ---------------- fp32 fallback (round-1, passed) if ws too small ----------------
__global__ __launch_bounds__(256) void diag_kernel(const float* __restrict__ x,
                                                   float* __restrict__ diag) {
    const int lane = threadIdx.x & 63;
    const int wave = threadIdx.x >> 6;
    const int row  = (blockIdx.x << 2) + wave;
    const float4 v = ((const float4*)(x + (size_t)row * NC))[lane];
    float s = v.x * v.x + v.y * v.y + v.z * v.z + v.w * v.w;
    #pragma unroll
    for (int off = 32; off; off >>= 1) s += __shfl_xor(s, off, 64);
    if (lane == 0) diag[row] = s;
}

#define FTI 64
#define FTJ 256
#define FKC 16

__global__ __launch_bounds__(256) void fcm_fallback(const float* __restrict__ x,
                                                    const float* __restrict__ diag,
                                                    float* __restrict__ out) {
    __shared__ float As[FKC * FTI];
    __shared__ float Bs[FKC * FTJ];
    __shared__ float Dsf[FTJ];
    __shared__ float Scrf[FTI * 32 * 3];

    const int tid = threadIdx.x;
    const int bx  = blockIdx.x;
    const int batch = (bx & 7) >> 1;
    const int tile  = ((bx >> 3) << 1) | (bx & 1);
    const int i0    = tile * FTI;
    const float* __restrict__ xb = x + (size_t)batch * NN * NC;
    const float* __restrict__ db = diag + (size_t)batch * NN;
    const int tx = tid & 31;
    const int ty = tid >> 5;
    const int sr  = tid & 63;
    const int sk0 = (tid >> 6) << 2;

    float m1[8], m2[8]; int i1[8];
    #pragma unroll
    for (int r = 0; r < 8; ++r) { m1[r] = FLT_MAX; m2[r] = FLT_MAX; i1[r] = 0; }

    for (int jt = 0; jt < NN / FTJ; ++jt) {
        const int j0 = jt * FTJ;
        __syncthreads();
        Dsf[tid] = db[j0 + tid];
        float acc[8][8];
        #pragma unroll
        for (int r = 0; r < 8; ++r)
            #pragma unroll
            for (int c = 0; c < 8; ++c) acc[r][c] = 0.0f;
        float4 pa  = *(const float4*)(xb + (size_t)(i0 + sr) * NC + sk0);
        const float* bsrc = xb + (size_t)(j0 + tid) * NC;
        float4 pb0 = *(const float4*)(bsrc + 0);
        float4 pb1 = *(const float4*)(bsrc + 4);
        float4 pb2 = *(const float4*)(bsrc + 8);
        float4 pb3 = *(const float4*)(bsrc + 12);
        for (int kc = 0; kc < NC / FKC; ++kc) {
            __syncthreads();
            As[(sk0 + 0) * FTI + sr] = pa.x;
            As[(sk0 + 1) * FTI + sr] = pa.y;
            As[(sk0 + 2) * FTI + sr] = pa.z;
            As[(sk0 + 3) * FTI + sr] = pa.w;
            Bs[ 0 * FTJ + tid] = pb0.x; Bs[ 1 * FTJ + tid] = pb0.y;
            Bs[ 2 * FTJ + tid] = pb0.z; Bs[ 3 * FTJ + tid] = pb0.w;
            Bs[ 4 * FTJ + tid] = pb1.x; Bs[ 5 * FTJ + tid] = pb1.y;
            Bs[ 6 * FTJ + tid] = pb1.z; Bs[ 7 * FTJ + tid] = pb1.w;
            Bs[ 8 * FTJ + tid] = pb2.x; Bs[ 9 * FTJ + tid] = pb2.y;
            Bs[10 * FTJ + tid] = pb2.z; Bs[11 * FTJ + tid] = pb2.w;
            Bs[12 * FTJ + tid] = pb3.x; Bs[13 * FTJ + tid] = pb3.y;
            Bs[14 * FTJ + tid] = pb3.z; Bs[15 * FTJ + tid] = pb3.w;
            if (kc + 1 < NC / FKC) {
                const int kb = (kc + 1) * FKC;
                pa  = *(const float4*)(xb + (size_t)(i0 + sr) * NC + kb + sk0);
                pb0 = *(const float4*)(bsrc + kb + 0);
                pb1 = *(const float4*)(bsrc + kb + 4);
                pb2 = *(const float4*)(bsrc + kb + 8);
                pb3 = *(const float4*)(bsrc + kb + 12);
            }
            __syncthreads();
            #pragma unroll
            for (int k = 0; k < FKC; ++k) {
                float av[8], bv[8];
                *(float4*)&av[0] = *(const float4*)&As[k * FTI + ty * 8];
                *(float4*)&av[4] = *(const float4*)&As[k * FTI + ty * 8 + 4];
                *(float4*)&bv[0] = *(const float4*)&Bs[k * FTJ + tx * 8];
                *(float4*)&bv[4] = *(const float4*)&Bs[k * FTJ + tx * 8 + 4];
                #pragma unroll
                for (int r = 0; r < 8; ++r)
                    #pragma unroll
                    for (int c = 0; c < 8; ++c)
                        acc[r][c] = fmaf(av[r], bv[c], acc[r][c]);
            }
        }
        #pragma unroll
        for (int c = 0; c < 8; ++c) {
            const int j = j0 + tx * 8 + c;
            const float dj = Dsf[tx * 8 + c];
            #pragma unroll
            for (int r = 0; r < 8; ++r) {
                const int ig = i0 + ty * 8 + r;
                float v = fmaf(-2.0f, acc[r][c], dj);
                v = (j == ig) ? FLT_MAX : v;
                const bool lt = v < m1[r];
                m2[r] = fminf(m2[r], fmaxf(m1[r], v));
                m1[r] = fminf(m1[r], v);
                i1[r] = lt ? j : i1[r];
            }
        }
    }
    __syncthreads();
    #pragma unroll
    for (int r = 0; r < 8; ++r) {
        float* s = &Scrf[((ty * 8 + r) * 32 + tx) * 3];
        s[0] = m1[r]; s[1] = __int_as_float(i1[r]); s[2] = m2[r];
    }
    __syncthreads();
    if (tid < FTI) {
        float M1 = FLT_MAX, M2 = FLT_MAX; int I1 = 0;
        for (int t = 0; t < 32; ++t) {
            const float* s = &Scrf[(tid * 32 + t) * 3];
            const float v1 = s[0]; const int ii = __float_as_int(s[1]);
            const float v2 = s[2];
            if (v1 < M1 || (v1 == M1 && ii < I1)) {
                M2 = fminf(M2, M1); M1 = v1; I1 = ii;
            } else {
                M2 = fminf(M2, v1);
            }
            M2 = fminf(M2, v2);
        }
        const int   gi = i0 + tid;
        const float di = db[gi];
        const float d1 = sqrtf(fmaxf(di + M1, 0.0f) + 1e-9f);
        const float d2 = sqrtf(fmaxf(di + M2, 0.0f) + 1e-9f);
        const float e  = expf(d1);
        const float pred = (d1 / d2 < 0.6f) ? 2.0f / (1.0f + e)
                                            : 2.0f / (1.0f + 2.0f * e);
        out[(size_t)batch * NN + gi] = pred;
        out[(size_t)NB * NN + (size_t)batch * NN + gi] = (float)I1;
    }
}

extern "C" void kernel_launch(void* const* d_in, const int* in_sizes, int n_in,
                              void* d_out, int out_size, void* d_ws, size_t ws_size,
                              hipStream_t stream) {
    const float* x = (const float*)d_in[0];
    float* out     = (float*)d_out;
    const size_t n_elem    = (size_t)NB * NN * NC;
    const size_t need      = n_elem * 2 * 2 + (size_t)NB * NN * 4;   // f16 hi/lo + diag
    const size_t part_b    = (size_t)NB * NS * NN * 16;              // partials (21 MB)
    const size_t need_sym  = need + part_b;
    if (ws_size >= need_sym) {
        f16*    xh   = (f16*)d_ws;
        f16*    xl   = xh + n_elem;
        float*  diag = (float*)(xl + n_elem);
        float4* P    = (float4*)((char*)d_ws + need);                // 16B-aligned
        prep_kernel<<<dim3(NB * NN / 4), dim3(256), 0, stream>>>(x, xh, xl, diag);
        hipMemsetAsync(P, 0x7f, part_b, stream);                     // huge-sentinel init
        fcm_sym<<<dim3(NB * NJOBS), dim3(256), 0, stream>>>(xh, xl, diag, P);
        fcm_reduce<<<dim3(NB * NN / 256), dim3(256), 0, stream>>>(P, diag, out);
    } else if (ws_size >= need) {
        f16*   xh   = (f16*)d_ws;
        f16*   xl   = xh + n_elem;
        float* diag = (float*)(xl + n_elem);
        prep_kernel<<<dim3(NB * NN / 4), dim3(256), 0, stream>>>(x, xh, xl, diag);
        fcm_mfma<<<dim3(256), dim3(256), 0, stream>>>(xh, xl, diag, out);
    } else {
        float* diag = (float*)d_ws;
        diag_kernel<<<dim3(NB * NN / 4), dim3(256), 0, stream>>>(x, diag);
        fcm_fallback<<<dim3(256), dim3(256), 0, stream>>>(x, diag, out);
    }
}